// Round 1
// baseline (3345.378 us; speedup 1.0000x reference)
//
#include <hip/hip_runtime.h>
#include <math.h>

#define N 4096
#define STEPS 16384
#define CHUNK 16
#define NCHUNK (STEPS / CHUNK)
#define MBLK 1024
#define SST 20   // padded stride (floats) for ST/SX: float4-aligned, 2-way-bank max (free)
#define NW (MBLK - 64)    // 960 worker threads (waves 1..15)
#define XBASE (4 * NW)    // 3840: first 3840 elements owned 4-per-worker
#define NX (N - XBASE)    // 256 extras owned 1-each by tid 64..319

// Workgroup barrier that does NOT drain vmcnt (LDS-only ordering between phases).
__device__ __forceinline__ void lgkm_barrier() {
  asm volatile("s_waitcnt lgkmcnt(0)\n\ts_barrier" ::: "memory");
}

// ---- prep: thr[t] = atanh(2u-1) in fp64; lastocc[t] = no later same-idx in chunk ----
__global__ __launch_bounds__(256) void pre_kernel(const float* __restrict__ u,
                                                  const int* __restrict__ idx,
                                                  double* __restrict__ thr,
                                                  int* __restrict__ lastocc) {
  int t = blockIdx.x * 256 + threadIdx.x;
  if (t < STEPS) {
    float r = 2.0f * u[t] - 1.0f;          // exact same fp32 rounding as reference
    double rd = (double)r;
    thr[t] = 0.5 * log((1.0 + rd) / (1.0 - rd));   // r=-1 -> -inf (tie->+1 matches ref)
    int cbase = t & ~(CHUNK - 1);
    int my = idx[t];
    int lo = 1;
    for (int tt = (t & (CHUNK - 1)) + 1; tt < CHUNK; ++tt)
      if (idx[cbase + tt] == my) { lo = 0; break; }
    lastocc[t] = lo;
  }
}

// ---- initial field: I0[row] = sum_k J[row,k]*m0[k] + h[row], fp64 accumulate ----
__global__ __launch_bounds__(256) void init_field_kernel(const float* __restrict__ J,
                                                         const float* __restrict__ h,
                                                         const float* __restrict__ m0,
                                                         double* __restrict__ I) {
  __shared__ double red[256];
  int row = blockIdx.x;
  const float4* Jr = (const float4*)(J + (size_t)row * N);
  const float4* mv = (const float4*)m0;
  double acc = 0.0;
  for (int q = threadIdx.x; q < N / 4; q += 256) {
    float4 a = Jr[q];
    float4 b = mv[q];
    acc += (double)(a.x * b.x) + (double)(a.y * b.y) +
           (double)(a.z * b.z) + (double)(a.w * b.w);
  }
  red[threadIdx.x] = acc;
  __syncthreads();
  for (int s = 128; s > 0; s >>= 1) {
    if (threadIdx.x < s) red[threadIdx.x] += red[threadIdx.x + s];
    __syncthreads();
  }
  if (threadIdx.x == 0) I[row] = red[0] + (double)h[row];
}

// ---- overlapped chunk-resolved Glauber chain: 1 workgroup, 1024 threads ----
// Per iteration k:
//   Phase 1 (concurrent): wave0 resolves chunk k flip-driven; while resolving,
//     it also accumulates xacc = cross-coupling corrections J[idx_k][idx_{k+1}]
//     for the NEXT chunk's 16 field values. Workers (waves 1-15) apply chunk
//     k-1's flips to the full fp64 field (global-load latency runs under the
//     resolve). Wave0 also stores the prefetched ST/SX blocks for k+1 and
//     issues gathers for k+2 (full-iteration slack).
//   Phase 2 (short): wave0 forms chunk-k+1 resolve inputs:
//     Ireg = field_lds[idx_{k+1}] (complete through k-1) + xacc (chunk k).
//     Workers pre-read chunk k's flip rows/count so their apply loads issue
//     at the next phase-1 entry.
// Barriers are lgkm-only; in-flight vmem (S gathers) crosses them.
__global__ __launch_bounds__(MBLK) void pbit_kernel(const float* __restrict__ J,
                                                    const float* __restrict__ m0,
                                                    const int* __restrict__ idx,
                                                    const double* __restrict__ thr,
                                                    const int* __restrict__ lastocc,
                                                    const double* __restrict__ I0,
                                                    float* __restrict__ out) {
  __shared__ __align__(16) double field_lds[N];        // 32 KB master field
  __shared__ __align__(16) float m_lds[N];             // 16 KB spins
  __shared__ __align__(16) float ST_lds[CHUNK * SST];  // ST[c*SST+r] = J[idx_k[r]][idx_k[c]]
  __shared__ __align__(16) float SX_lds[CHUNK * SST];  // SX[c*SST+r] = J[idx_k[r]][idx_{k+1}[c]]
  __shared__ __align__(16) int   pubi_lds[2][CHUNK];   // double-buffered flip rows
  __shared__ __align__(16) float pubd_lds[2][CHUNK];   // double-buffered deltas (+/-2)
  __shared__ int pubF_lds[2];                          // flip counts

  const int tid = threadIdx.x;

  // field_lds init by launch layout (independent of apply ownership)
  {
    const double* ip = I0 + 4 * tid;
    double a = ip[0], b = ip[1], c = ip[2], d = ip[3];
    *(double2*)(field_lds + 4 * tid + 0) = make_double2(a, b);
    *(double2*)(field_lds + 4 * tid + 2) = make_double2(c, d);
  }
  ((float4*)m_lds)[tid] = ((const float4*)m0)[tid];
  if (tid == 0) { pubF_lds[0] = 0; pubF_lds[1] = 0; }

  const int t16 = tid & 15;       // step slot within chunk
  const int gt = tid >> 2;        // gather row slot (wave0: 0..15)
  const int gq = (tid & 3) * 4;   // gather col group

  // ---- worker (waves 1-15) field ownership: fp64 registers + LDS write-through ----
  const bool isw = (tid >= 64);
  const int wid = isw ? (tid - 64) : 0;
  const bool isx = isw && (tid < 64 + NX);
  double i0 = 0.0, i1 = 0.0, i2 = 0.0, i3 = 0.0, i4 = 0.0;
  if (isw) {
    const double* ip = I0 + 4 * wid;
    i0 = ip[0]; i1 = ip[1]; i2 = ip[2]; i3 = ip[3];
    if (isx) i4 = I0[XBASE + wid];
  }
  const float* Jb = J + 4 * (size_t)wid;
  const float* Jx = J + XBASE + (size_t)wid;
  int rows[CHUNK];
  int Fprev = 0;

  // ---- wave0 pipeline registers ----
  int mi = 0, ni = 0, mlo = 0, nlo = 0;
  double mt = 0.0, nt = 0.0;
  float fST0 = 0, fST1 = 0, fST2 = 0, fST3 = 0;
  float fSX0 = 0, fSX1 = 0, fSX2 = 0, fSX3 = 0;
  double Ireg = 0.0, xacc = 0.0;
  float mym = 0.0f;

  if (tid < 64) {
    mi = idx[t16];      mt = thr[t16];      mlo = lastocc[t16];
    ni = idx[16 + t16]; nt = thr[16 + t16]; nlo = lastocc[16 + t16];
    // synchronous gather: ST(0)=J[idx0][idx0], SX(0->1)=J[idx0][idx1]
    int r0 = idx[gt];
    int c0 = idx[gq], c1 = idx[gq + 1], c2 = idx[gq + 2], c3 = idx[gq + 3];
    int x0 = idx[16 + gq], x1 = idx[16 + gq + 1], x2 = idx[16 + gq + 2], x3 = idx[16 + gq + 3];
    const float* Jr = J + (size_t)r0 * N;
    ST_lds[(gq + 0) * SST + gt] = Jr[c0];
    ST_lds[(gq + 1) * SST + gt] = Jr[c1];
    ST_lds[(gq + 2) * SST + gt] = Jr[c2];
    ST_lds[(gq + 3) * SST + gt] = Jr[c3];
    SX_lds[(gq + 0) * SST + gt] = Jr[x0];
    SX_lds[(gq + 1) * SST + gt] = Jr[x1];
    SX_lds[(gq + 2) * SST + gt] = Jr[x2];
    SX_lds[(gq + 3) * SST + gt] = Jr[x3];
    // async gather: ST(1)=J[idx1][idx1], SX(1->2)=J[idx1][idx2]
    int r1 = idx[16 + gt];
    int y0 = idx[32 + gq], y1 = idx[32 + gq + 1], y2 = idx[32 + gq + 2], y3 = idx[32 + gq + 3];
    const float* Jg = J + (size_t)r1 * N;
    fST0 = Jg[x0]; fST1 = Jg[x1]; fST2 = Jg[x2]; fST3 = Jg[x3];
    fSX0 = Jg[y0]; fSX1 = Jg[y1]; fSX2 = Jg[y2]; fSX3 = Jg[y3];
  }
  __syncthreads();
  if (tid < 64) {
    Ireg = field_lds[mi];   // I0 value for chunk 0
    mym = m_lds[mi];
  }

  int cur = 0;
  for (int k = 0; k < NCHUNK; ++k) {
    const int prv = cur ^ 1;
    // ================= Phase 1 (concurrent) =================
    if (isw) {
      // apply chunk k-1's flips (rows[]/Fprev preloaded in previous phase 2;
      // loads issue immediately, latency hides under wave0's resolve)
      if (Fprev > 0) {
#pragma unroll
        for (int b = 0; b < CHUNK; b += 8) {
          if (b < Fprev) {                  // uniform
            float4 rr[8];
            float rx[8] = {0, 0, 0, 0, 0, 0, 0, 0};
#pragma unroll
            for (int t = 0; t < 8; ++t)
              if (b + t < Fprev) rr[t] = *(const float4*)(Jb + (size_t)rows[b + t] * N);
            if (isx) {                      // waves 1-4: extra owned element
#pragma unroll
              for (int t = 0; t < 8; ++t)
                if (b + t < Fprev) rx[t] = Jx[(size_t)rows[b + t] * N];
            }
            float a0 = 0.f, a1 = 0.f, a2 = 0.f, a3 = 0.f, ax = 0.f;
#pragma unroll
            for (int t = 0; t < 8; ++t)
              if (b + t < Fprev) {
                float dvt = pubd_lds[prv][b + t];
                a0 += rr[t].x * dvt; a1 += rr[t].y * dvt;
                a2 += rr[t].z * dvt; a3 += rr[t].w * dvt;
                ax += rx[t] * dvt;
              }
            i0 += (double)a0; i1 += (double)a1;
            i2 += (double)a2; i3 += (double)a3;
            if (isx) i4 += (double)ax;
          }
        }
        *(double2*)(field_lds + 4 * wid + 0) = make_double2(i0, i1);
        *(double2*)(field_lds + 4 * wid + 2) = make_double2(i2, i3);
        if (isx) field_lds[XBASE + wid] = i4;
      }
    } else {
      // pipeline loads: chunk k+2 step data + gather addresses; chunk k+3 SX cols
      int b2 = k * CHUNK + 2 * CHUNK; if (b2 >= STEPS) b2 = 0;   // clamp: unused on final chunks
      int b3 = k * CHUNK + 3 * CHUNK; if (b3 >= STEPS) b3 = 0;
      int n2i = idx[b2 + t16];
      double n2t = thr[b2 + t16];
      int n2lo = lastocc[b2 + t16];
      int g2row = idx[b2 + gt];
      int tc0 = idx[b2 + gq], tc1 = idx[b2 + gq + 1], tc2 = idx[b2 + gq + 2], tc3 = idx[b2 + gq + 3];
      int uc0 = idx[b3 + gq], uc1 = idx[b3 + gq + 1], uc2 = idx[b3 + gq + 2], uc3 = idx[b3 + gq + 3];
      // ---- resolve chunk k (register-only chain) ----
      const float* sp = &ST_lds[t16 * SST];
      float4 sA = *(const float4*)(sp + 0);
      float4 sB = *(const float4*)(sp + 4);
      float4 sC = *(const float4*)(sp + 8);
      float4 sD = *(const float4*)(sp + 12);
      const float* xp = &SX_lds[t16 * SST];
      float4 xA = *(const float4*)(xp + 0);
      float4 xB = *(const float4*)(xp + 4);
      float4 xC = *(const float4*)(xp + 8);
      float4 xD = *(const float4*)(xp + 12);
      double Ival = Ireg;
      float mcur = mym;
      float finals = 0.0f, finald = 0.0f;
      int conf = -1;
      bool locked = false;
      while (true) {
        float s = (Ival >= mt) ? 1.0f : -1.0f;   // I >= atanh(r) <=> tanh(I) >= r
        float dl = s - mcur;
        unsigned long long mask = __ballot(dl != 0.0f) & 0xFFFFull;
        mask &= (~0ull) << (conf + 1);
        if (mask == 0) {
          if (!locked) { finals = s; finald = 0.0f; }
          break;
        }
        int f = (int)__builtin_ctzll(mask);      // wave-uniform
        if (!locked && t16 <= f) { finals = s; finald = dl; locked = true; }
        float dl_f = __int_as_float(__builtin_amdgcn_readlane(__float_as_int(dl), f));
        float s_f  = __int_as_float(__builtin_amdgcn_readlane(__float_as_int(s), f));
        int   i_f  = __builtin_amdgcn_readlane(mi, f);
        float xcol, xnx;                          // Scol[f], SXcol[f]; f uniform -> scalar branches
        switch (f) {
          case 0:  xcol = sA.x; xnx = xA.x; break;  case 1:  xcol = sA.y; xnx = xA.y; break;
          case 2:  xcol = sA.z; xnx = xA.z; break;  case 3:  xcol = sA.w; xnx = xA.w; break;
          case 4:  xcol = sB.x; xnx = xB.x; break;  case 5:  xcol = sB.y; xnx = xB.y; break;
          case 6:  xcol = sB.z; xnx = xB.z; break;  case 7:  xcol = sB.w; xnx = xB.w; break;
          case 8:  xcol = sC.x; xnx = xC.x; break;  case 9:  xcol = sC.y; xnx = xC.y; break;
          case 10: xcol = sC.z; xnx = xC.z; break;  case 11: xcol = sC.w; xnx = xC.w; break;
          case 12: xcol = sD.x; xnx = xD.x; break;  case 13: xcol = sD.y; xnx = xD.y; break;
          default: if (f == 14) { xcol = sD.z; xnx = xD.z; }
                   else         { xcol = sD.w; xnx = xD.w; } break;
        }
        Ival += (double)(xcol * dl_f);            // exact product: dl in {-2,2}
        xacc += (double)(xnx * dl_f);             // cross-correction for chunk k+1, lane t16
        if (mi == i_f) mcur = s_f;                // in-chunk duplicate index
        conf = f;
      }
      // publish compacted flip list + m updates (last occurrence wins)
      unsigned long long fm = __ballot((tid < 16) && (finald != 0.0f));
      if (tid < 16) {
        if (finald != 0.0f) {
          int pos = __popcll(fm & ((1ull << t16) - 1ull));
          pubi_lds[cur][pos] = mi;
          pubd_lds[cur][pos] = finald;
        }
        if (mlo) m_lds[mi] = finals;
        if (tid == 0) pubF_lds[cur] = __popcll(fm);
      }
      // store ST(k+1)/SX(k+1->k+2) (gathers issued one full iteration ago)
      ST_lds[(gq + 0) * SST + gt] = fST0;
      ST_lds[(gq + 1) * SST + gt] = fST1;
      ST_lds[(gq + 2) * SST + gt] = fST2;
      ST_lds[(gq + 3) * SST + gt] = fST3;
      SX_lds[(gq + 0) * SST + gt] = fSX0;
      SX_lds[(gq + 1) * SST + gt] = fSX1;
      SX_lds[(gq + 2) * SST + gt] = fSX2;
      SX_lds[(gq + 3) * SST + gt] = fSX3;
      // issue gathers for ST(k+2)/SX(k+2->k+3): consumed next iteration
      const float* Jg = J + (size_t)g2row * N;
      fST0 = Jg[tc0]; fST1 = Jg[tc1]; fST2 = Jg[tc2]; fST3 = Jg[tc3];
      fSX0 = Jg[uc0]; fSX1 = Jg[uc1]; fSX2 = Jg[uc2]; fSX3 = Jg[uc3];
      // rotate step-data pipeline
      mi = ni; mt = nt; mlo = nlo;
      ni = n2i; nt = n2t; nlo = n2lo;
    }
    lgkm_barrier();
    // ================= Phase 2 (short) =================
    if (tid < 64) {
      // field_lds now complete through chunk k-1; xacc supplies chunk k's terms
      Ireg = field_lds[mi] + xacc;   // mi = chunk k+1 index (rotated)
      mym = m_lds[mi];               // spins complete through chunk k
      xacc = 0.0;
    } else {
      // pre-read chunk k's flip list so apply loads issue at next phase-1 entry
      Fprev = pubF_lds[cur];
      if (Fprev > 0) {
        int4 ra = *(const int4*)(pubi_lds[cur] + 0);
        int4 rb = *(const int4*)(pubi_lds[cur] + 4);
        int4 rc = *(const int4*)(pubi_lds[cur] + 8);
        int4 rd = *(const int4*)(pubi_lds[cur] + 12);
        rows[0] = ra.x;  rows[1] = ra.y;  rows[2] = ra.z;  rows[3] = ra.w;
        rows[4] = rb.x;  rows[5] = rb.y;  rows[6] = rb.z;  rows[7] = rb.w;
        rows[8] = rc.x;  rows[9] = rc.y;  rows[10] = rc.z; rows[11] = rc.w;
        rows[12] = rd.x; rows[13] = rd.y; rows[14] = rd.z; rows[15] = rd.w;
      }
    }
    lgkm_barrier();
    cur ^= 1;
  }

  __syncthreads();
  ((float4*)out)[tid] = ((const float4*)m_lds)[tid];
}

extern "C" void kernel_launch(void* const* d_in, const int* in_sizes, int n_in,
                              void* d_out, int out_size, void* d_ws, size_t ws_size,
                              hipStream_t stream) {
  const float* J = (const float*)d_in[0];
  const float* h = (const float*)d_in[1];
  const float* m0 = (const float*)d_in[2];
  const int* idx = (const int*)d_in[3];
  const float* u = (const float*)d_in[4];
  float* out = (float*)d_out;

  double* thr = (double*)d_ws;                                        // 16384 f64
  double* I0 = (double*)((char*)d_ws + STEPS * sizeof(double));       // 4096 f64
  int* lastocc = (int*)((char*)d_ws + STEPS * sizeof(double)
                                    + N * sizeof(double));            // 16384 i32

  pre_kernel<<<dim3(STEPS / 256), dim3(256), 0, stream>>>(u, idx, thr, lastocc);
  init_field_kernel<<<dim3(N), dim3(256), 0, stream>>>(J, h, m0, I0);
  pbit_kernel<<<dim3(1), dim3(MBLK), 0, stream>>>(J, m0, idx, thr, lastocc, I0, out);
}